// Round 5
// baseline (578.155 us; speedup 1.0000x reference)
//
#include <hip/hip_runtime.h>
#include <hip/hip_bf16.h>
#include <cstdint>
#include <cstddef>

#define IN_DIM 512
#define OUT_DIM 256
#define BROWS 256          // rows per coarse bucket (bucket = row >> 8)
#define NBUCK_MAX 512      // supports M <= 131072 (col packed in 17 bits)
#define CAP 9216           // LDS record capacity per bucket (mean 8184 @ E=3.2M)

typedef __bf16 bf16x8 __attribute__((ext_vector_type(8)));
typedef float f32x4 __attribute__((ext_vector_type(4)));

__device__ __forceinline__ unsigned short f2bf(float f) {
    __bf16 h = (__bf16)f;
    return __builtin_bit_cast(unsigned short, h);
}
__device__ __forceinline__ float bf2f(unsigned short u) {
    unsigned int x = ((unsigned int)u) << 16;
    return __builtin_bit_cast(float, x);
}
__device__ __forceinline__ float selu(float x) {
    const float kScale = 1.0507009873554805f;
    const float kAlpha = 1.6732632423543772f;
    return (x > 0.f) ? kScale * x : kScale * kAlpha * (expf(x) - 1.f);
}

// ---------------- W convert + transpose: [512,256] f32 -> Wt [256,512] bf16 ----
__global__ void k_convW(const float* __restrict__ W, unsigned short* __restrict__ Wt) {
    int idx = blockIdx.x * 256 + threadIdx.x;   // 0..131071
    int n = idx & (OUT_DIM - 1);
    int k = idx >> 8;
    if (k < IN_DIM) Wt[n * IN_DIM + k] = f2bf(W[k * OUT_DIM + n]);
}

// ---------------- GEMM: xw = features @ W -> per-row-scaled INT8 --------------
__launch_bounds__(512, 2)
__global__ void k_gemm(const float* __restrict__ A, const unsigned short* __restrict__ Wt,
                       signed char* __restrict__ xq, float* __restrict__ scales, int M) {
    __shared__ unsigned short lA[128 * 32];   // 8 KB
    __shared__ unsigned short lB[256 * 32];   // 16 KB
    __shared__ float lrm[128];                // per-row absmax (float bits, >=0)
    const int t = threadIdx.x;
    const int wave = t >> 6, lane = t & 63;
    const int wr = wave >> 2, wc = wave & 3;   // 2 wave-rows x 4 wave-cols
    const int m0 = blockIdx.x * 128;
    const int mlo = lane & 15, kq = lane >> 4;

    if (t < 128) lrm[t] = 0.f;                // covered by first loop barrier

    f32x4 acc[4][4] = {};

    for (int k0 = 0; k0 < IN_DIM; k0 += 32) {
        // stage A: 128x32 f32 -> bf16 LDS; 1024 float4 chunks / 512 threads = 2
        #pragma unroll
        for (int p = 0; p < 2; ++p) {
            int idx = p * 512 + t;
            int r = idx >> 3, c4 = idx & 7;
            int gr = m0 + r; if (gr >= M) gr = M - 1;   // clamp
            const float4 v = *reinterpret_cast<const float4*>(&A[(size_t)gr * IN_DIM + k0 + c4 * 4]);
            ushort4 u;
            u.x = f2bf(v.x); u.y = f2bf(v.y); u.z = f2bf(v.z); u.w = f2bf(v.w);
            *reinterpret_cast<ushort4*>(&lA[r * 32 + c4 * 4]) = u;
        }
        // stage B: 256x32 bf16; 1024 x 16B chunks / 512 threads = 2
        #pragma unroll
        for (int p = 0; p < 2; ++p) {
            int idx = p * 512 + t;
            int n = idx >> 2, c8 = idx & 3;
            const uint4 v = *reinterpret_cast<const uint4*>(&Wt[(size_t)n * IN_DIM + k0 + c8 * 8]);
            *reinterpret_cast<uint4*>(&lB[n * 32 + c8 * 8]) = v;
        }
        __syncthreads();

        bf16x8 af[4], bfr[4];
        #pragma unroll
        for (int mt = 0; mt < 4; ++mt)
            af[mt] = *reinterpret_cast<const bf16x8*>(&lA[(wr * 64 + mt * 16 + mlo) * 32 + kq * 8]);
        #pragma unroll
        for (int nt = 0; nt < 4; ++nt)
            bfr[nt] = *reinterpret_cast<const bf16x8*>(&lB[(wc * 64 + nt * 16 + mlo) * 32 + kq * 8]);
        #pragma unroll
        for (int mt = 0; mt < 4; ++mt)
            #pragma unroll
            for (int nt = 0; nt < 4; ++nt)
                acc[mt][nt] = __builtin_amdgcn_mfma_f32_16x16x32_bf16(af[mt], bfr[nt], acc[mt][nt], 0, 0, 0);
        __syncthreads();
    }

    // ---- per-row absmax: C/D layout col=wc*64+nt*16+mlo, row=wr*64+mt*16+kq*4+i
    #pragma unroll
    for (int mt = 0; mt < 4; ++mt) {
        #pragma unroll
        for (int i = 0; i < 4; ++i) {
            float m = fmaxf(fmaxf(fabsf(acc[mt][0][i]), fabsf(acc[mt][1][i])),
                            fmaxf(fabsf(acc[mt][2][i]), fabsf(acc[mt][3][i])));
            m = fmaxf(m, __shfl_xor(m, 1));
            m = fmaxf(m, __shfl_xor(m, 2));
            m = fmaxf(m, __shfl_xor(m, 4));
            m = fmaxf(m, __shfl_xor(m, 8));
            if (mlo == 0)
                atomicMax(reinterpret_cast<int*>(&lrm[wr * 64 + mt * 16 + kq * 4 + i]),
                          __float_as_int(m));   // all values >= 0: float bits monotone
        }
    }
    __syncthreads();

    // ---- quantize + store int8
    #pragma unroll
    for (int mt = 0; mt < 4; ++mt) {
        #pragma unroll
        for (int i = 0; i < 4; ++i) {
            const int rl = wr * 64 + mt * 16 + kq * 4 + i;
            const int row = m0 + rl;
            const float rm = lrm[rl];
            const float inv = (rm > 0.f) ? (127.f / rm) : 0.f;
            if (row < M) {
                #pragma unroll
                for (int nt = 0; nt < 4; ++nt) {
                    int q = (int)rintf(acc[mt][nt][i] * inv);   // |q| <= 127 by construction
                    xq[(size_t)row * OUT_DIM + wc * 64 + nt * 16 + mlo] = (signed char)q;
                }
            }
        }
    }
    if (t < 128) {
        int row = m0 + t;
        if (row < M) scales[row] = lrm[t] * (1.f / 127.f);
    }
}

// ---------------- bucket-level histogram ---------------------------------------
__launch_bounds__(512)
__global__ void k_bhist(const int* __restrict__ rows, int* __restrict__ bcnt, int E) {
    __shared__ int cnt[NBUCK_MAX];
    const int t = threadIdx.x;
    const int base = blockIdx.x * 8192;
    cnt[t] = 0;
    __syncthreads();
    #pragma unroll
    for (int p = 0; p < 4; ++p) {
        const int i = base + p * 2048 + (t << 2);
        if (i + 4 <= E) {
            int4 r4 = *reinterpret_cast<const int4*>(&rows[i]);
            atomicAdd(&cnt[r4.x >> 8], 1);
            atomicAdd(&cnt[r4.y >> 8], 1);
            atomicAdd(&cnt[r4.z >> 8], 1);
            atomicAdd(&cnt[r4.w >> 8], 1);
        } else if (i < E) {
            for (int j = i; j < E && j < i + 4; ++j) atomicAdd(&cnt[rows[j] >> 8], 1);
        }
    }
    __syncthreads();
    if (cnt[t] > 0) atomicAdd(&bcnt[t], cnt[t]);
}

// ---------------- bucket scan: bbase = exclusive-scan(bcnt); bcursor = bbase --
__launch_bounds__(NBUCK_MAX)
__global__ void k_bscan(const int* __restrict__ bcnt, int* __restrict__ bbase,
                        int* __restrict__ bcursor, int nbuck, int E) {
    const int t = threadIdx.x;
    __shared__ int sh[NBUCK_MAX];
    int v = (t < nbuck) ? bcnt[t] : 0;
    sh[t] = v;
    __syncthreads();
    for (int off = 1; off < NBUCK_MAX; off <<= 1) {
        int x = (t >= off) ? sh[t - off] : 0;
        __syncthreads();
        sh[t] += x;
        __syncthreads();
    }
    int ex = sh[t] - v;          // for t >= nbuck this equals E (v=0)
    bbase[t] = ex;
    bcursor[t] = ex;
    if (t == 0) bbase[NBUCK_MAX] = E;
}

// ---------------- Pass A: block-aggregated coarse binning ---------------------
// Folds the per-col dequant scale into the stored edge value:
// binned.y = val * scales[col]  -> downstream needs zero scale loads.
__launch_bounds__(512)
__global__ void k_bin(const int* __restrict__ rows, const int* __restrict__ cols,
                      const float* __restrict__ vals, const float* __restrict__ scales,
                      int* __restrict__ bcursor, int2* __restrict__ binned, int E) {
    __shared__ int cnt[NBUCK_MAX];     // counts, then reused as running local cursor
    __shared__ int scn[NBUCK_MAX];     // scan workspace
    __shared__ int dlt[NBUCK_MAX];     // global_base - local_exclusive_base
    const int t = threadIdx.x;
    const int base = blockIdx.x * 8192;

    cnt[t] = 0;
    __syncthreads();

    // load 16 edges/thread, statically indexed (rule #20: no runtime-indexed regs)
    int er[16], ec[16];
    float ev[16];
    #pragma unroll
    for (int p = 0; p < 4; ++p) {
        const int i = base + p * 2048 + (t << 2);
        if (i + 4 <= E) {
            int4 r4 = *reinterpret_cast<const int4*>(&rows[i]);
            int4 c4 = *reinterpret_cast<const int4*>(&cols[i]);
            float4 v4 = *reinterpret_cast<const float4*>(&vals[i]);
            er[4*p+0] = r4.x; ec[4*p+0] = c4.x; ev[4*p+0] = v4.x * scales[c4.x];
            er[4*p+1] = r4.y; ec[4*p+1] = c4.y; ev[4*p+1] = v4.y * scales[c4.y];
            er[4*p+2] = r4.z; ec[4*p+2] = c4.z; ev[4*p+2] = v4.z * scales[c4.z];
            er[4*p+3] = r4.w; ec[4*p+3] = c4.w; ev[4*p+3] = v4.w * scales[c4.w];
        } else {
            #pragma unroll
            for (int j = 0; j < 4; ++j) {
                int idx = i + j;
                bool ok = idx < E;
                er[4*p+j] = ok ? rows[idx] : -1;
                ec[4*p+j] = ok ? cols[idx] : 0;
                ev[4*p+j] = ok ? vals[idx] * scales[cols[idx]] : 0.f;
            }
        }
    }

    // count per bucket
    #pragma unroll
    for (int k = 0; k < 16; ++k)
        if (er[k] >= 0) atomicAdd(&cnt[er[k] >> 8], 1);
    __syncthreads();

    // block scan (Hillis-Steele over 512 slots, 512 threads)
    int v = cnt[t];
    scn[t] = v;
    __syncthreads();
    for (int off = 1; off < NBUCK_MAX; off <<= 1) {
        int x = (t >= off) ? scn[t - off] : 0;
        __syncthreads();
        scn[t] += x;
        __syncthreads();
    }
    int ex = scn[t] - v;   // exclusive prefix of this bucket within the block

    // reserve global chunk per non-empty bucket (one atomic per bucket per block)
    int d = 0;
    if (v > 0) d = atomicAdd(&bcursor[t], v) - ex;
    dlt[t] = d;
    cnt[t] = ex;           // reuse as running local cursor
    __syncthreads();

    // write records: global pos = dlt[bucket] + local_rank
    #pragma unroll
    for (int k = 0; k < 16; ++k) {
        if (er[k] >= 0) {
            int b = er[k] >> 8;
            int lp = atomicAdd(&cnt[b], 1);
            binned[(size_t)(dlt[b] + lp)] =
                make_int2(ec[k] | ((er[k] & 255) << 17), __float_as_int(ev[k]));
        }
    }
}

// ---------------- fused bucket sort + aggregation + epilogue ------------------
// One 512-thread block per 256-row bucket. Sort the bucket's records into LDS
// (count -> scan -> scatter, all block-local: replaces k_fine2, ecv, and rs),
// then 8 waves each aggregate 32 rows with U=8 in-flight int8 gathers and the
// fused skip+bias+SELU epilogue. binned.y already holds val*scale[col].
__launch_bounds__(512)
__global__ void k_aggb(const signed char* __restrict__ xq,
                       const float* __restrict__ scales,
                       const int2* __restrict__ binned,
                       const int* __restrict__ bbase,
                       const float* __restrict__ skipw,
                       const float* __restrict__ bias,
                       float* __restrict__ out, int M) {
    __shared__ int2 lrec[CAP];         // 72 KB sorted records
    __shared__ int lrs[BROWS + 1];     // row starts (local)
    __shared__ int lcur[BROWS];        // counters / cursors
    const int b = blockIdx.x, t = threadIdx.x;
    const int wave = t >> 6, lane = t & 63;
    const int start = bbase[b], end = bbase[b + 1];
    const int cnt = end - start;
    const int d4 = lane * 4;

    if (cnt <= CAP) {
        if (t < BROWS) lcur[t] = 0;
        __syncthreads();
        // phase 1: count rows
        for (int i = start + t; i < end; i += 512)
            atomicAdd(&lcur[binned[i].x >> 17], 1);
        __syncthreads();
        // inclusive scan of 256 counters (first 256 threads)
        int v = 0;
        if (t < BROWS) { v = lcur[t]; lrs[t] = v; }
        __syncthreads();
        for (int off = 1; off < BROWS; off <<= 1) {
            int x = 0;
            if (t < BROWS && t >= off) x = lrs[t - off];
            __syncthreads();
            if (t < BROWS) lrs[t] += x;
            __syncthreads();
        }
        int ex = 0;
        if (t < BROWS) ex = lrs[t] - v;     // exclusive prefix
        __syncthreads();
        if (t < BROWS) { lrs[t] = ex; lcur[t] = ex; }
        if (t == 0) lrs[BROWS] = cnt;
        __syncthreads();
        // phase 2: scatter into sorted LDS array
        for (int i = start + t; i < end; i += 512) {
            int2 rec = binned[i];
            int pos = atomicAdd(&lcur[rec.x >> 17], 1);
            lrec[pos] = rec;
        }
        __syncthreads();
        // phase 3: per-wave row aggregation (32 rows/wave)
        for (int rr = 0; rr < BROWS / 8; ++rr) {
            const int r = wave * (BROWS / 8) + rr;
            const int grow = b * BROWS + r;
            if (grow >= M) continue;
            const int s = lrs[r], e = lrs[r + 1];
            float a0 = 0.f, a1 = 0.f, a2 = 0.f, a3 = 0.f;
            int p = s;
            for (; p + 8 <= e; p += 8) {
                int cs[8]; float vs[8];
                #pragma unroll
                for (int u = 0; u < 8; ++u) {
                    int2 c = lrec[p + u];           // uniform addr -> LDS broadcast
                    cs[u] = c.x & 0x1FFFF; vs[u] = __int_as_float(c.y);
                }
                int g[8];
                #pragma unroll
                for (int u = 0; u < 8; ++u)
                    g[u] = *reinterpret_cast<const int*>(&xq[(size_t)cs[u] * OUT_DIM + d4]);
                #pragma unroll
                for (int u = 0; u < 8; ++u) {
                    a0 += vs[u] * (float)(signed char)(g[u]);
                    a1 += vs[u] * (float)(signed char)(g[u] >> 8);
                    a2 += vs[u] * (float)(signed char)(g[u] >> 16);
                    a3 += vs[u] * (float)(g[u] >> 24);
                }
            }
            for (; p < e; ++p) {
                int2 c = lrec[p];
                float v2 = __int_as_float(c.y);
                int g = *reinterpret_cast<const int*>(&xq[(size_t)(c.x & 0x1FFFF) * OUT_DIM + d4]);
                a0 += v2 * (float)(signed char)(g);
                a1 += v2 * (float)(signed char)(g >> 8);
                a2 += v2 * (float)(signed char)(g >> 16);
                a3 += v2 * (float)(g >> 24);
            }
            // epilogue: skip + bias + selu
            int w = *reinterpret_cast<const int*>(&xq[(size_t)grow * OUT_DIM + d4]);
            float sc = scales[grow];
            float x0 = (float)(signed char)(w)        * sc;
            float x1 = (float)(signed char)(w >> 8)   * sc;
            float x2 = (float)(signed char)(w >> 16)  * sc;
            float x3 = (float)(w >> 24)               * sc;
            float4 sw = *reinterpret_cast<const float4*>(&skipw[d4]);
            float4 bi = *reinterpret_cast<const float4*>(&bias[d4]);
            float4 r4;
            r4.x = selu(a0 + x0 * sw.x + bi.x);
            r4.y = selu(a1 + x1 * sw.y + bi.y);
            r4.z = selu(a2 + x2 * sw.z + bi.z);
            r4.w = selu(a3 + x3 * sw.w + bi.w);
            *reinterpret_cast<float4*>(&out[(size_t)grow * OUT_DIM + d4]) = r4;
        }
    } else {
        // overflow fallback (unreachable for uniform input): unsorted direct scan
        for (int rr = 0; rr < BROWS / 8; ++rr) {
            const int r = wave * (BROWS / 8) + rr;
            const int grow = b * BROWS + r;
            if (grow >= M) continue;
            float a0 = 0.f, a1 = 0.f, a2 = 0.f, a3 = 0.f;
            for (int i = start; i < end; ++i) {
                int2 c = binned[i];
                if ((c.x >> 17) != r) continue;
                float v2 = __int_as_float(c.y);
                int g = *reinterpret_cast<const int*>(&xq[(size_t)(c.x & 0x1FFFF) * OUT_DIM + d4]);
                a0 += v2 * (float)(signed char)(g);
                a1 += v2 * (float)(signed char)(g >> 8);
                a2 += v2 * (float)(signed char)(g >> 16);
                a3 += v2 * (float)(g >> 24);
            }
            int w = *reinterpret_cast<const int*>(&xq[(size_t)grow * OUT_DIM + d4]);
            float sc = scales[grow];
            float x0 = (float)(signed char)(w)        * sc;
            float x1 = (float)(signed char)(w >> 8)   * sc;
            float x2 = (float)(signed char)(w >> 16)  * sc;
            float x3 = (float)(w >> 24)               * sc;
            float4 sw = *reinterpret_cast<const float4*>(&skipw[d4]);
            float4 bi = *reinterpret_cast<const float4*>(&bias[d4]);
            float4 r4;
            r4.x = selu(a0 + x0 * sw.x + bi.x);
            r4.y = selu(a1 + x1 * sw.y + bi.y);
            r4.z = selu(a2 + x2 * sw.z + bi.z);
            r4.w = selu(a3 + x3 * sw.w + bi.w);
            *reinterpret_cast<float4*>(&out[(size_t)grow * OUT_DIM + d4]) = r4;
        }
    }
}

// ---------------- fallback path kernels (use_binned == false) -----------------
__global__ void k_hist(const int* __restrict__ rows, int* __restrict__ counts, int E) {
    int i = (blockIdx.x * 256 + threadIdx.x) * 4;
    if (i + 4 <= E) {
        int4 r = *reinterpret_cast<const int4*>(&rows[i]);
        atomicAdd(&counts[r.x], 1);
        atomicAdd(&counts[r.y], 1);
        atomicAdd(&counts[r.z], 1);
        atomicAdd(&counts[r.w], 1);
    } else {
        for (int j = i; j < E; ++j) atomicAdd(&counts[rows[j]], 1);
    }
}

__global__ void k_scan1(const int* __restrict__ counts, int* __restrict__ rs,
                        int* __restrict__ bsum, int N) {
    int b = blockIdx.x, t = threadIdx.x;
    int base = b * 1024 + t * 4;
    int4 v = make_int4(0, 0, 0, 0);
    if (base + 4 <= N) v = *reinterpret_cast<const int4*>(&counts[base]);
    else {
        if (base + 0 < N) v.x = counts[base + 0];
        if (base + 1 < N) v.y = counts[base + 1];
        if (base + 2 < N) v.z = counts[base + 2];
        if (base + 3 < N) v.w = counts[base + 3];
    }
    int s0 = v.x, s1 = s0 + v.y, s2 = s1 + v.z, s3 = s2 + v.w;
    __shared__ int sh[256];
    sh[t] = s3; __syncthreads();
    for (int off = 1; off < 256; off <<= 1) {
        int x = (t >= off) ? sh[t - off] : 0;
        __syncthreads();
        sh[t] += x;
        __syncthreads();
    }
    int ex = sh[t] - s3;
    if (base + 0 < N) rs[base + 0] = ex;
    if (base + 1 < N) rs[base + 1] = ex + s0;
    if (base + 2 < N) rs[base + 2] = ex + s1;
    if (base + 3 < N) rs[base + 3] = ex + s2;
    if (t == 255) bsum[b] = sh[255];
}

__global__ void k_scan2(const int* __restrict__ bsum, int* __restrict__ boff, int nb) {
    int t = threadIdx.x;
    __shared__ int sh[256];
    int v = (t < nb) ? bsum[t] : 0;
    sh[t] = v; __syncthreads();
    for (int off = 1; off < 256; off <<= 1) {
        int x = (t >= off) ? sh[t - off] : 0;
        __syncthreads();
        sh[t] += x;
        __syncthreads();
    }
    if (t < nb) boff[t] = sh[t] - v;
}

__global__ void k_scan3(int* __restrict__ rs, int* __restrict__ cursor,
                        const int* __restrict__ boff, int N, int E) {
    int b = blockIdx.x, t = threadIdx.x;
    int base = b * 1024 + t * 4;
    int o = boff[b];
    #pragma unroll
    for (int j = 0; j < 4; ++j) {
        if (base + j < N) {
            int v = rs[base + j] + o;
            rs[base + j] = v;
            cursor[base + j] = v;
        }
    }
    if (b == 0 && t == 0) rs[N] = E;
}

__global__ void k_scatter(const int* __restrict__ rows, const int* __restrict__ cols,
                          const float* __restrict__ vals, const float* __restrict__ scales,
                          int* __restrict__ cursor, int2* __restrict__ ecv, int E) {
    int i = (blockIdx.x * 256 + threadIdx.x) * 4;
    if (i + 4 <= E) {
        int4 r = *reinterpret_cast<const int4*>(&rows[i]);
        int4 c = *reinterpret_cast<const int4*>(&cols[i]);
        float4 v = *reinterpret_cast<const float4*>(&vals[i]);
        int p0 = atomicAdd(&cursor[r.x], 1); ecv[p0] = make_int2(c.x, __float_as_int(v.x * scales[c.x]));
        int p1 = atomicAdd(&cursor[r.y], 1); ecv[p1] = make_int2(c.y, __float_as_int(v.y * scales[c.y]));
        int p2 = atomicAdd(&cursor[r.z], 1); ecv[p2] = make_int2(c.z, __float_as_int(v.z * scales[c.z]));
        int p3 = atomicAdd(&cursor[r.w], 1); ecv[p3] = make_int2(c.w, __float_as_int(v.w * scales[c.w]));
    } else {
        for (int j = i; j < E; ++j) {
            int p = atomicAdd(&cursor[rows[j]], 1);
            ecv[p] = make_int2(cols[j], __float_as_int(vals[j] * scales[cols[j]]));
        }
    }
}

__launch_bounds__(256)
__global__ void k_agg(const signed char* __restrict__ xq,
                      const float* __restrict__ scales,
                      const int2* __restrict__ ecv,
                      const int* __restrict__ rs,
                      const float* __restrict__ skipw,
                      const float* __restrict__ bias,
                      float* __restrict__ out, int M) {
    const int wave = threadIdx.x >> 6, lane = threadIdx.x & 63;
    const int node = blockIdx.x * 4 + wave;
    if (node >= M) return;
    const int s = __builtin_amdgcn_readfirstlane(rs[node]);
    const int e = __builtin_amdgcn_readfirstlane(rs[node + 1]);
    const int d4 = lane * 4;

    float a0 = 0.f, a1 = 0.f, a2 = 0.f, a3 = 0.f;
    int p = s;
    constexpr int U = 8;
    for (; p + U <= e; p += U) {
        int   cs[U];
        float vs[U];
        #pragma unroll
        for (int u = 0; u < U; ++u) {
            int2 c = ecv[p + u];
            cs[u] = c.x; vs[u] = __int_as_float(c.y);
        }
        int g[U];
        #pragma unroll
        for (int u = 0; u < U; ++u)
            g[u] = *reinterpret_cast<const int*>(&xq[(size_t)cs[u] * OUT_DIM + d4]);
        #pragma unroll
        for (int u = 0; u < U; ++u) {
            a0 += vs[u] * (float)(signed char)(g[u]);
            a1 += vs[u] * (float)(signed char)(g[u] >> 8);
            a2 += vs[u] * (float)(signed char)(g[u] >> 16);
            a3 += vs[u] * (float)(g[u] >> 24);
        }
    }
    for (; p < e; ++p) {
        int2 c = ecv[p];
        float v = __int_as_float(c.y);
        int g = *reinterpret_cast<const int*>(&xq[(size_t)c.x * OUT_DIM + d4]);
        a0 += v * (float)(signed char)(g);
        a1 += v * (float)(signed char)(g >> 8);
        a2 += v * (float)(signed char)(g >> 16);
        a3 += v * (float)(g >> 24);
    }

    int w = *reinterpret_cast<const int*>(&xq[(size_t)node * OUT_DIM + d4]);
    float sc = scales[node];
    float x0 = (float)(signed char)(w)        * sc;
    float x1 = (float)(signed char)(w >> 8)   * sc;
    float x2 = (float)(signed char)(w >> 16)  * sc;
    float x3 = (float)(w >> 24)               * sc;

    float4 sw = *reinterpret_cast<const float4*>(&skipw[d4]);
    float4 bi = *reinterpret_cast<const float4*>(&bias[d4]);
    float4 r;
    r.x = selu(a0 + x0 * sw.x + bi.x);
    r.y = selu(a1 + x1 * sw.y + bi.y);
    r.z = selu(a2 + x2 * sw.z + bi.z);
    r.w = selu(a3 + x3 * sw.w + bi.w);
    *reinterpret_cast<float4*>(&out[(size_t)node * OUT_DIM + d4]) = r;
}

extern "C" void kernel_launch(void* const* d_in, const int* in_sizes, int n_in,
                              void* d_out, int out_size, void* d_ws, size_t ws_size,
                              hipStream_t stream) {
    const float* features = (const float*)d_in[0];
    const int*   adj_rows = (const int*)d_in[1];
    const int*   adj_cols = (const int*)d_in[2];
    const float* adj_vals = (const float*)d_in[3];
    const float* Wk       = (const float*)d_in[4];
    const float* bias     = (const float*)d_in[5];
    const float* skipw    = (const float*)d_in[6];
    float* out = (float*)d_out;

    const int M = in_sizes[0] / IN_DIM;     // 100000
    const int E = in_sizes[1];              // 3200000

    char* w = (char*)d_ws;
    size_t off = 0;
    auto carve = [&](size_t bytes) -> void* {
        void* p = w + off;
        off = (off + bytes + 255) & ~(size_t)255;
        return p;
    };
    signed char* xq = (signed char*)carve((size_t)M * OUT_DIM);             // 25.6 MB
    float* scales   = (float*)carve((size_t)M * 4);                         // 0.4 MB
    unsigned short* Wt = (unsigned short*)carve((size_t)IN_DIM * OUT_DIM * 2);
    int*  counts = (int*)carve((size_t)M * 4);
    int*  rs     = (int*)carve((size_t)(M + 1) * 4);
    int*  cursor = (int*)carve((size_t)M * 4);
    int*  bsum   = (int*)carve(256 * 4);
    int*  boff   = (int*)carve(256 * 4);
    int*  bcnt   = (int*)carve((NBUCK_MAX + 1) * 4);
    int*  bbase  = (int*)carve((NBUCK_MAX + 1) * 4);
    int*  bcur   = (int*)carve((NBUCK_MAX + 1) * 4);
    int2* ecv    = (int2*)carve((size_t)E * 8);                             // 25.6 MB (fallback only)
    int2* binned = (int2*)carve((size_t)E * 8);                             // 25.6 MB
    const int nbuck = (M + BROWS - 1) / BROWS;
    const bool use_binned = (off <= ws_size) && (nbuck <= NBUCK_MAX) && (M <= (1 << 17));

    k_convW<<<(IN_DIM * OUT_DIM + 255) / 256, 256, 0, stream>>>(Wk, Wt);
    k_gemm<<<(M + 127) / 128, 512, 0, stream>>>(features, Wt, xq, scales, M);

    if (use_binned) {
        hipMemsetAsync(bcnt, 0, (NBUCK_MAX + 1) * 4, stream);
        k_bhist<<<(E + 8191) / 8192, 512, 0, stream>>>(adj_rows, bcnt, E);
        k_bscan<<<1, NBUCK_MAX, 0, stream>>>(bcnt, bbase, bcur, nbuck, E);
        k_bin<<<(E + 8191) / 8192, 512, 0, stream>>>(adj_rows, adj_cols, adj_vals, scales, bcur, binned, E);
        k_aggb<<<nbuck, 512, 0, stream>>>(xq, scales, binned, bbase, skipw, bias, out, M);
    } else {
        hipMemsetAsync(counts, 0, (size_t)M * 4, stream);
        k_hist<<<(E / 4 + 255) / 256, 256, 0, stream>>>(adj_rows, counts, E);
        int nb = (M + 1023) / 1024;
        k_scan1<<<nb, 256, 0, stream>>>(counts, rs, bsum, M);
        k_scan2<<<1, 256, 0, stream>>>(bsum, boff, nb);
        k_scan3<<<nb, 256, 0, stream>>>(rs, cursor, boff, M, E);
        k_scatter<<<(E / 4 + 255) / 256, 256, 0, stream>>>(adj_rows, adj_cols, adj_vals, scales, cursor, ecv, E);
        k_agg<<<(M + 3) / 4, 256, 0, stream>>>(xq, scales, ecv, rs, skipw, bias, out, M);
    }
}

// Round 6
// 556.548 us; speedup vs baseline: 1.0388x; 1.0388x over previous
//
#include <hip/hip_runtime.h>
#include <hip/hip_bf16.h>
#include <cstdint>
#include <cstddef>

#define IN_DIM 512
#define OUT_DIM 256
#define BROWS 128          // rows per bucket (bucket = row >> 7)
#define NBUCK_MAX 1024     // supports M <= 131072 (col packed in 17 bits)
#define CAP 4608           // LDS record capacity per bucket (mean 4092 @ E=3.2M)

typedef __bf16 bf16x8 __attribute__((ext_vector_type(8)));
typedef float f32x4 __attribute__((ext_vector_type(4)));

__device__ __forceinline__ unsigned short f2bf(float f) {
    __bf16 h = (__bf16)f;
    return __builtin_bit_cast(unsigned short, h);
}
__device__ __forceinline__ float bf2f(unsigned short u) {
    unsigned int x = ((unsigned int)u) << 16;
    return __builtin_bit_cast(float, x);
}
__device__ __forceinline__ float selu(float x) {
    const float kScale = 1.0507009873554805f;
    const float kAlpha = 1.6732632423543772f;
    return (x > 0.f) ? kScale * x : kScale * kAlpha * (expf(x) - 1.f);
}

// ---------------- W convert + transpose: [512,256] f32 -> Wt [256,512] bf16 ----
__global__ void k_convW(const float* __restrict__ W, unsigned short* __restrict__ Wt) {
    int idx = blockIdx.x * 256 + threadIdx.x;   // 0..131071
    int n = idx & (OUT_DIM - 1);
    int k = idx >> 8;
    if (k < IN_DIM) Wt[n * IN_DIM + k] = f2bf(W[k * OUT_DIM + n]);
}

// ---------------- GEMM: xw = features @ W -> per-row-scaled INT8 --------------
__launch_bounds__(512, 2)
__global__ void k_gemm(const float* __restrict__ A, const unsigned short* __restrict__ Wt,
                       signed char* __restrict__ xq, float* __restrict__ scales, int M) {
    __shared__ unsigned short lA[128 * 32];   // 8 KB
    __shared__ unsigned short lB[256 * 32];   // 16 KB
    __shared__ float lrm[128];                // per-row absmax (float bits, >=0)
    const int t = threadIdx.x;
    const int wave = t >> 6, lane = t & 63;
    const int wr = wave >> 2, wc = wave & 3;   // 2 wave-rows x 4 wave-cols
    const int m0 = blockIdx.x * 128;
    const int mlo = lane & 15, kq = lane >> 4;

    if (t < 128) lrm[t] = 0.f;                // covered by first loop barrier

    f32x4 acc[4][4] = {};

    for (int k0 = 0; k0 < IN_DIM; k0 += 32) {
        // stage A: 128x32 f32 -> bf16 LDS; 1024 float4 chunks / 512 threads = 2
        #pragma unroll
        for (int p = 0; p < 2; ++p) {
            int idx = p * 512 + t;
            int r = idx >> 3, c4 = idx & 7;
            int gr = m0 + r; if (gr >= M) gr = M - 1;   // clamp
            const float4 v = *reinterpret_cast<const float4*>(&A[(size_t)gr * IN_DIM + k0 + c4 * 4]);
            ushort4 u;
            u.x = f2bf(v.x); u.y = f2bf(v.y); u.z = f2bf(v.z); u.w = f2bf(v.w);
            *reinterpret_cast<ushort4*>(&lA[r * 32 + c4 * 4]) = u;
        }
        // stage B: 256x32 bf16; 1024 x 16B chunks / 512 threads = 2
        #pragma unroll
        for (int p = 0; p < 2; ++p) {
            int idx = p * 512 + t;
            int n = idx >> 2, c8 = idx & 3;
            const uint4 v = *reinterpret_cast<const uint4*>(&Wt[(size_t)n * IN_DIM + k0 + c8 * 8]);
            *reinterpret_cast<uint4*>(&lB[n * 32 + c8 * 8]) = v;
        }
        __syncthreads();

        bf16x8 af[4], bfr[4];
        #pragma unroll
        for (int mt = 0; mt < 4; ++mt)
            af[mt] = *reinterpret_cast<const bf16x8*>(&lA[(wr * 64 + mt * 16 + mlo) * 32 + kq * 8]);
        #pragma unroll
        for (int nt = 0; nt < 4; ++nt)
            bfr[nt] = *reinterpret_cast<const bf16x8*>(&lB[(wc * 64 + nt * 16 + mlo) * 32 + kq * 8]);
        #pragma unroll
        for (int mt = 0; mt < 4; ++mt)
            #pragma unroll
            for (int nt = 0; nt < 4; ++nt)
                acc[mt][nt] = __builtin_amdgcn_mfma_f32_16x16x32_bf16(af[mt], bfr[nt], acc[mt][nt], 0, 0, 0);
        __syncthreads();
    }

    // ---- per-row absmax: C/D layout col=wc*64+nt*16+mlo, row=wr*64+mt*16+kq*4+i
    #pragma unroll
    for (int mt = 0; mt < 4; ++mt) {
        #pragma unroll
        for (int i = 0; i < 4; ++i) {
            float m = fmaxf(fmaxf(fabsf(acc[mt][0][i]), fabsf(acc[mt][1][i])),
                            fmaxf(fabsf(acc[mt][2][i]), fabsf(acc[mt][3][i])));
            m = fmaxf(m, __shfl_xor(m, 1));
            m = fmaxf(m, __shfl_xor(m, 2));
            m = fmaxf(m, __shfl_xor(m, 4));
            m = fmaxf(m, __shfl_xor(m, 8));
            if (mlo == 0)
                atomicMax(reinterpret_cast<int*>(&lrm[wr * 64 + mt * 16 + kq * 4 + i]),
                          __float_as_int(m));   // all values >= 0: float bits monotone
        }
    }
    __syncthreads();

    // ---- quantize + store int8
    #pragma unroll
    for (int mt = 0; mt < 4; ++mt) {
        #pragma unroll
        for (int i = 0; i < 4; ++i) {
            const int rl = wr * 64 + mt * 16 + kq * 4 + i;
            const int row = m0 + rl;
            const float rm = lrm[rl];
            const float inv = (rm > 0.f) ? (127.f / rm) : 0.f;
            if (row < M) {
                #pragma unroll
                for (int nt = 0; nt < 4; ++nt) {
                    int q = (int)rintf(acc[mt][nt][i] * inv);   // |q| <= 127 by construction
                    xq[(size_t)row * OUT_DIM + wc * 64 + nt * 16 + mlo] = (signed char)q;
                }
            }
        }
    }
    if (t < 128) {
        int row = m0 + t;
        if (row < M) scales[row] = lrm[t] * (1.f / 127.f);
    }
}

// ---------------- bucket-level histogram (1024 buckets, LDS-aggregated) -------
__launch_bounds__(512)
__global__ void k_bhist(const int* __restrict__ rows, int* __restrict__ bcnt, int E) {
    __shared__ int cnt[NBUCK_MAX];
    const int t = threadIdx.x;
    const int base = blockIdx.x * 8192;
    cnt[t] = 0; cnt[t + 512] = 0;
    __syncthreads();
    #pragma unroll
    for (int p = 0; p < 4; ++p) {
        const int i = base + p * 2048 + (t << 2);
        if (i + 4 <= E) {
            int4 r4 = *reinterpret_cast<const int4*>(&rows[i]);
            atomicAdd(&cnt[r4.x >> 7], 1);
            atomicAdd(&cnt[r4.y >> 7], 1);
            atomicAdd(&cnt[r4.z >> 7], 1);
            atomicAdd(&cnt[r4.w >> 7], 1);
        } else if (i < E) {
            for (int j = i; j < E && j < i + 4; ++j) atomicAdd(&cnt[rows[j] >> 7], 1);
        }
    }
    __syncthreads();
    if (cnt[t] > 0) atomicAdd(&bcnt[t], cnt[t]);
    if (cnt[t + 512] > 0) atomicAdd(&bcnt[t + 512], cnt[t + 512]);
}

// ---------------- bucket scan (1024 threads) ----------------------------------
__launch_bounds__(NBUCK_MAX)
__global__ void k_bscan(const int* __restrict__ bcnt, int* __restrict__ bbase,
                        int* __restrict__ bcursor, int nbuck, int E) {
    const int t = threadIdx.x;
    __shared__ int sh[NBUCK_MAX];
    int v = (t < nbuck) ? bcnt[t] : 0;
    sh[t] = v;
    __syncthreads();
    for (int off = 1; off < NBUCK_MAX; off <<= 1) {
        int x = (t >= off) ? sh[t - off] : 0;
        __syncthreads();
        sh[t] += x;
        __syncthreads();
    }
    int ex = sh[t] - v;          // for t >= nbuck this equals E (v=0)
    bbase[t] = ex;
    bcursor[t] = ex;
    if (t == 0) bbase[NBUCK_MAX] = E;
}

// ---------------- Pass A: block-aggregated coarse binning ---------------------
// 1024-bucket scan done pairwise by 512 threads (thread t owns buckets 2t,2t+1).
// Folds per-col dequant scale into record value: binned.y = val * scales[col].
// Record: x = col | (row&127)<<17.
__launch_bounds__(512)
__global__ void k_bin(const int* __restrict__ rows, const int* __restrict__ cols,
                      const float* __restrict__ vals, const float* __restrict__ scales,
                      int* __restrict__ bcursor, int2* __restrict__ binned, int E) {
    __shared__ int cnt[NBUCK_MAX];     // counts, then reused as running local cursor
    __shared__ int scn[512];           // pairwise scan workspace
    __shared__ int dlt[NBUCK_MAX];     // global_base - local_exclusive_base
    const int t = threadIdx.x;
    const int base = blockIdx.x * 8192;

    cnt[t] = 0; cnt[t + 512] = 0;
    __syncthreads();

    // load 16 edges/thread, statically indexed (rule #20: no runtime-indexed regs)
    int er[16], ec[16];
    float ev[16];
    #pragma unroll
    for (int p = 0; p < 4; ++p) {
        const int i = base + p * 2048 + (t << 2);
        if (i + 4 <= E) {
            int4 r4 = *reinterpret_cast<const int4*>(&rows[i]);
            int4 c4 = *reinterpret_cast<const int4*>(&cols[i]);
            float4 v4 = *reinterpret_cast<const float4*>(&vals[i]);
            er[4*p+0] = r4.x; ec[4*p+0] = c4.x; ev[4*p+0] = v4.x * scales[c4.x];
            er[4*p+1] = r4.y; ec[4*p+1] = c4.y; ev[4*p+1] = v4.y * scales[c4.y];
            er[4*p+2] = r4.z; ec[4*p+2] = c4.z; ev[4*p+2] = v4.z * scales[c4.z];
            er[4*p+3] = r4.w; ec[4*p+3] = c4.w; ev[4*p+3] = v4.w * scales[c4.w];
        } else {
            #pragma unroll
            for (int j = 0; j < 4; ++j) {
                int idx = i + j;
                bool ok = idx < E;
                er[4*p+j] = ok ? rows[idx] : -1;
                ec[4*p+j] = ok ? cols[idx] : 0;
                ev[4*p+j] = ok ? vals[idx] * scales[cols[idx]] : 0.f;
            }
        }
    }

    // count per bucket
    #pragma unroll
    for (int k = 0; k < 16; ++k)
        if (er[k] >= 0) atomicAdd(&cnt[er[k] >> 7], 1);
    __syncthreads();

    // pairwise block scan: thread t owns buckets 2t, 2t+1
    int v0 = cnt[2 * t], v1 = cnt[2 * t + 1];
    int s = v0 + v1;
    scn[t] = s;
    __syncthreads();
    for (int off = 1; off < 512; off <<= 1) {
        int x = (t >= off) ? scn[t - off] : 0;
        __syncthreads();
        scn[t] += x;
        __syncthreads();
    }
    int exp_ = scn[t] - s;         // exclusive prefix of pair
    int ex0 = exp_, ex1 = exp_ + v0;

    // reserve global chunk per non-empty bucket (one atomic per bucket per block)
    int d0 = 0, d1 = 0;
    if (v0 > 0) d0 = atomicAdd(&bcursor[2 * t], v0) - ex0;
    if (v1 > 0) d1 = atomicAdd(&bcursor[2 * t + 1], v1) - ex1;
    dlt[2 * t] = d0; dlt[2 * t + 1] = d1;
    cnt[2 * t] = ex0; cnt[2 * t + 1] = ex1;   // reuse as running local cursor
    __syncthreads();

    // write records: global pos = dlt[bucket] + local_rank
    #pragma unroll
    for (int k = 0; k < 16; ++k) {
        if (er[k] >= 0) {
            int b = er[k] >> 7;
            int lp = atomicAdd(&cnt[b], 1);
            binned[(size_t)(dlt[b] + lp)] =
                make_int2(ec[k] | ((er[k] & 127) << 17), __float_as_int(ev[k]));
        }
    }
}

// ---------------- fused bucket sort + aggregation + epilogue ------------------
// One 512-thread block per 128-row bucket; LDS 38 KB -> 4 blocks/CU = 32 waves
// (full occupancy; round-5's 72KB/2-block variant stalled at 29% occupancy).
// Sort bucket records into LDS (count -> scan -> scatter), then 8 waves each
// aggregate 16 rows with U=8 in-flight int8 gathers + fused epilogue.
__launch_bounds__(512)
__global__ void k_aggb(const signed char* __restrict__ xq,
                       const float* __restrict__ scales,
                       const int2* __restrict__ binned,
                       const int* __restrict__ bbase,
                       const float* __restrict__ skipw,
                       const float* __restrict__ bias,
                       float* __restrict__ out, int M) {
    __shared__ int2 lrec[CAP];         // 36 KB sorted records
    __shared__ int lrs[BROWS + 1];     // row starts (local)
    __shared__ int lcur[BROWS];        // counters / cursors
    const int b = blockIdx.x, t = threadIdx.x;
    const int wave = t >> 6, lane = t & 63;
    const int start = bbase[b], end = bbase[b + 1];
    const int cnt = end - start;
    const int d4 = lane * 4;

    if (cnt <= CAP) {
        if (t < BROWS) lcur[t] = 0;
        __syncthreads();
        // phase 1: count rows
        for (int i = start + t; i < end; i += 512)
            atomicAdd(&lcur[binned[i].x >> 17], 1);
        __syncthreads();
        // scan of 128 counters (first 128 threads)
        int v = 0;
        if (t < BROWS) { v = lcur[t]; lrs[t] = v; }
        __syncthreads();
        for (int off = 1; off < BROWS; off <<= 1) {
            int x = 0;
            if (t < BROWS && t >= off) x = lrs[t - off];
            __syncthreads();
            if (t < BROWS) lrs[t] += x;
            __syncthreads();
        }
        int ex = 0;
        if (t < BROWS) ex = lrs[t] - v;     // exclusive prefix
        __syncthreads();
        if (t < BROWS) { lrs[t] = ex; lcur[t] = ex; }
        if (t == 0) lrs[BROWS] = cnt;
        __syncthreads();
        // phase 2: scatter into sorted LDS array
        for (int i = start + t; i < end; i += 512) {
            int2 rec = binned[i];
            int pos = atomicAdd(&lcur[rec.x >> 17], 1);
            lrec[pos] = rec;
        }
        __syncthreads();
        // phase 3: per-wave row aggregation (16 rows/wave)
        for (int rr = 0; rr < BROWS / 8; ++rr) {
            const int r = wave * (BROWS / 8) + rr;
            const int grow = b * BROWS + r;
            if (grow >= M) continue;
            const int s = lrs[r], e = lrs[r + 1];
            float a0 = 0.f, a1 = 0.f, a2 = 0.f, a3 = 0.f;
            int p = s;
            for (; p + 8 <= e; p += 8) {
                int cs[8]; float vs[8];
                #pragma unroll
                for (int u = 0; u < 8; ++u) {
                    int2 c = lrec[p + u];           // uniform addr -> LDS broadcast
                    cs[u] = c.x & 0x1FFFF; vs[u] = __int_as_float(c.y);
                }
                int g[8];
                #pragma unroll
                for (int u = 0; u < 8; ++u)
                    g[u] = *reinterpret_cast<const int*>(&xq[(size_t)cs[u] * OUT_DIM + d4]);
                #pragma unroll
                for (int u = 0; u < 8; ++u) {
                    a0 += vs[u] * (float)(signed char)(g[u]);
                    a1 += vs[u] * (float)(signed char)(g[u] >> 8);
                    a2 += vs[u] * (float)(signed char)(g[u] >> 16);
                    a3 += vs[u] * (float)(g[u] >> 24);
                }
            }
            for (; p < e; ++p) {
                int2 c = lrec[p];
                float v2 = __int_as_float(c.y);
                int g = *reinterpret_cast<const int*>(&xq[(size_t)(c.x & 0x1FFFF) * OUT_DIM + d4]);
                a0 += v2 * (float)(signed char)(g);
                a1 += v2 * (float)(signed char)(g >> 8);
                a2 += v2 * (float)(signed char)(g >> 16);
                a3 += v2 * (float)(g >> 24);
            }
            // epilogue: skip + bias + selu
            int w = *reinterpret_cast<const int*>(&xq[(size_t)grow * OUT_DIM + d4]);
            float sc = scales[grow];
            float x0 = (float)(signed char)(w)        * sc;
            float x1 = (float)(signed char)(w >> 8)   * sc;
            float x2 = (float)(signed char)(w >> 16)  * sc;
            float x3 = (float)(w >> 24)               * sc;
            float4 sw = *reinterpret_cast<const float4*>(&skipw[d4]);
            float4 bi = *reinterpret_cast<const float4*>(&bias[d4]);
            float4 r4;
            r4.x = selu(a0 + x0 * sw.x + bi.x);
            r4.y = selu(a1 + x1 * sw.y + bi.y);
            r4.z = selu(a2 + x2 * sw.z + bi.z);
            r4.w = selu(a3 + x3 * sw.w + bi.w);
            *reinterpret_cast<float4*>(&out[(size_t)grow * OUT_DIM + d4]) = r4;
        }
    } else {
        // overflow fallback (unreachable for uniform input): unsorted direct scan
        for (int rr = 0; rr < BROWS / 8; ++rr) {
            const int r = wave * (BROWS / 8) + rr;
            const int grow = b * BROWS + r;
            if (grow >= M) continue;
            float a0 = 0.f, a1 = 0.f, a2 = 0.f, a3 = 0.f;
            for (int i = start; i < end; ++i) {
                int2 c = binned[i];
                if ((c.x >> 17) != r) continue;
                float v2 = __int_as_float(c.y);
                int g = *reinterpret_cast<const int*>(&xq[(size_t)(c.x & 0x1FFFF) * OUT_DIM + d4]);
                a0 += v2 * (float)(signed char)(g);
                a1 += v2 * (float)(signed char)(g >> 8);
                a2 += v2 * (float)(signed char)(g >> 16);
                a3 += v2 * (float)(g >> 24);
            }
            int w = *reinterpret_cast<const int*>(&xq[(size_t)grow * OUT_DIM + d4]);
            float sc = scales[grow];
            float x0 = (float)(signed char)(w)        * sc;
            float x1 = (float)(signed char)(w >> 8)   * sc;
            float x2 = (float)(signed char)(w >> 16)  * sc;
            float x3 = (float)(w >> 24)               * sc;
            float4 sw = *reinterpret_cast<const float4*>(&skipw[d4]);
            float4 bi = *reinterpret_cast<const float4*>(&bias[d4]);
            float4 r4;
            r4.x = selu(a0 + x0 * sw.x + bi.x);
            r4.y = selu(a1 + x1 * sw.y + bi.y);
            r4.z = selu(a2 + x2 * sw.z + bi.z);
            r4.w = selu(a3 + x3 * sw.w + bi.w);
            *reinterpret_cast<float4*>(&out[(size_t)grow * OUT_DIM + d4]) = r4;
        }
    }
}

// ---------------- fallback path kernels (use_binned == false) -----------------
__global__ void k_hist(const int* __restrict__ rows, int* __restrict__ counts, int E) {
    int i = (blockIdx.x * 256 + threadIdx.x) * 4;
    if (i + 4 <= E) {
        int4 r = *reinterpret_cast<const int4*>(&rows[i]);
        atomicAdd(&counts[r.x], 1);
        atomicAdd(&counts[r.y], 1);
        atomicAdd(&counts[r.z], 1);
        atomicAdd(&counts[r.w], 1);
    } else {
        for (int j = i; j < E; ++j) atomicAdd(&counts[rows[j]], 1);
    }
}

__global__ void k_scan1(const int* __restrict__ counts, int* __restrict__ rs,
                        int* __restrict__ bsum, int N) {
    int b = blockIdx.x, t = threadIdx.x;
    int base = b * 1024 + t * 4;
    int4 v = make_int4(0, 0, 0, 0);
    if (base + 4 <= N) v = *reinterpret_cast<const int4*>(&counts[base]);
    else {
        if (base + 0 < N) v.x = counts[base + 0];
        if (base + 1 < N) v.y = counts[base + 1];
        if (base + 2 < N) v.z = counts[base + 2];
        if (base + 3 < N) v.w = counts[base + 3];
    }
    int s0 = v.x, s1 = s0 + v.y, s2 = s1 + v.z, s3 = s2 + v.w;
    __shared__ int sh[256];
    sh[t] = s3; __syncthreads();
    for (int off = 1; off < 256; off <<= 1) {
        int x = (t >= off) ? sh[t - off] : 0;
        __syncthreads();
        sh[t] += x;
        __syncthreads();
    }
    int ex = sh[t] - s3;
    if (base + 0 < N) rs[base + 0] = ex;
    if (base + 1 < N) rs[base + 1] = ex + s0;
    if (base + 2 < N) rs[base + 2] = ex + s1;
    if (base + 3 < N) rs[base + 3] = ex + s2;
    if (t == 255) bsum[b] = sh[255];
}

__global__ void k_scan2(const int* __restrict__ bsum, int* __restrict__ boff, int nb) {
    int t = threadIdx.x;
    __shared__ int sh[256];
    int v = (t < nb) ? bsum[t] : 0;
    sh[t] = v; __syncthreads();
    for (int off = 1; off < 256; off <<= 1) {
        int x = (t >= off) ? sh[t - off] : 0;
        __syncthreads();
        sh[t] += x;
        __syncthreads();
    }
    if (t < nb) boff[t] = sh[t] - v;
}

__global__ void k_scan3(int* __restrict__ rs, int* __restrict__ cursor,
                        const int* __restrict__ boff, int N, int E) {
    int b = blockIdx.x, t = threadIdx.x;
    int base = b * 1024 + t * 4;
    int o = boff[b];
    #pragma unroll
    for (int j = 0; j < 4; ++j) {
        if (base + j < N) {
            int v = rs[base + j] + o;
            rs[base + j] = v;
            cursor[base + j] = v;
        }
    }
    if (b == 0 && t == 0) rs[N] = E;
}

__global__ void k_scatter(const int* __restrict__ rows, const int* __restrict__ cols,
                          const float* __restrict__ vals, const float* __restrict__ scales,
                          int* __restrict__ cursor, int2* __restrict__ ecv, int E) {
    int i = (blockIdx.x * 256 + threadIdx.x) * 4;
    if (i + 4 <= E) {
        int4 r = *reinterpret_cast<const int4*>(&rows[i]);
        int4 c = *reinterpret_cast<const int4*>(&cols[i]);
        float4 v = *reinterpret_cast<const float4*>(&vals[i]);
        int p0 = atomicAdd(&cursor[r.x], 1); ecv[p0] = make_int2(c.x, __float_as_int(v.x * scales[c.x]));
        int p1 = atomicAdd(&cursor[r.y], 1); ecv[p1] = make_int2(c.y, __float_as_int(v.y * scales[c.y]));
        int p2 = atomicAdd(&cursor[r.z], 1); ecv[p2] = make_int2(c.z, __float_as_int(v.z * scales[c.z]));
        int p3 = atomicAdd(&cursor[r.w], 1); ecv[p3] = make_int2(c.w, __float_as_int(v.w * scales[c.w]));
    } else {
        for (int j = i; j < E; ++j) {
            int p = atomicAdd(&cursor[rows[j]], 1);
            ecv[p] = make_int2(cols[j], __float_as_int(vals[j] * scales[cols[j]]));
        }
    }
}

__launch_bounds__(256)
__global__ void k_agg(const signed char* __restrict__ xq,
                      const float* __restrict__ scales,
                      const int2* __restrict__ ecv,
                      const int* __restrict__ rs,
                      const float* __restrict__ skipw,
                      const float* __restrict__ bias,
                      float* __restrict__ out, int M) {
    const int wave = threadIdx.x >> 6, lane = threadIdx.x & 63;
    const int node = blockIdx.x * 4 + wave;
    if (node >= M) return;
    const int s = __builtin_amdgcn_readfirstlane(rs[node]);
    const int e = __builtin_amdgcn_readfirstlane(rs[node + 1]);
    const int d4 = lane * 4;

    float a0 = 0.f, a1 = 0.f, a2 = 0.f, a3 = 0.f;
    int p = s;
    constexpr int U = 8;
    for (; p + U <= e; p += U) {
        int   cs[U];
        float vs[U];
        #pragma unroll
        for (int u = 0; u < U; ++u) {
            int2 c = ecv[p + u];
            cs[u] = c.x; vs[u] = __int_as_float(c.y);
        }
        int g[U];
        #pragma unroll
        for (int u = 0; u < U; ++u)
            g[u] = *reinterpret_cast<const int*>(&xq[(size_t)cs[u] * OUT_DIM + d4]);
        #pragma unroll
        for (int u = 0; u < U; ++u) {
            a0 += vs[u] * (float)(signed char)(g[u]);
            a1 += vs[u] * (float)(signed char)(g[u] >> 8);
            a2 += vs[u] * (float)(signed char)(g[u] >> 16);
            a3 += vs[u] * (float)(g[u] >> 24);
        }
    }
    for (; p < e; ++p) {
        int2 c = ecv[p];
        float v = __int_as_float(c.y);
        int g = *reinterpret_cast<const int*>(&xq[(size_t)c.x * OUT_DIM + d4]);
        a0 += v * (float)(signed char)(g);
        a1 += v * (float)(signed char)(g >> 8);
        a2 += v * (float)(signed char)(g >> 16);
        a3 += v * (float)(g >> 24);
    }

    int w = *reinterpret_cast<const int*>(&xq[(size_t)node * OUT_DIM + d4]);
    float sc = scales[node];
    float x0 = (float)(signed char)(w)        * sc;
    float x1 = (float)(signed char)(w >> 8)   * sc;
    float x2 = (float)(signed char)(w >> 16)  * sc;
    float x3 = (float)(w >> 24)               * sc;

    float4 sw = *reinterpret_cast<const float4*>(&skipw[d4]);
    float4 bi = *reinterpret_cast<const float4*>(&bias[d4]);
    float4 r;
    r.x = selu(a0 + x0 * sw.x + bi.x);
    r.y = selu(a1 + x1 * sw.y + bi.y);
    r.z = selu(a2 + x2 * sw.z + bi.z);
    r.w = selu(a3 + x3 * sw.w + bi.w);
    *reinterpret_cast<float4*>(&out[(size_t)node * OUT_DIM + d4]) = r;
}

extern "C" void kernel_launch(void* const* d_in, const int* in_sizes, int n_in,
                              void* d_out, int out_size, void* d_ws, size_t ws_size,
                              hipStream_t stream) {
    const float* features = (const float*)d_in[0];
    const int*   adj_rows = (const int*)d_in[1];
    const int*   adj_cols = (const int*)d_in[2];
    const float* adj_vals = (const float*)d_in[3];
    const float* Wk       = (const float*)d_in[4];
    const float* bias     = (const float*)d_in[5];
    const float* skipw    = (const float*)d_in[6];
    float* out = (float*)d_out;

    const int M = in_sizes[0] / IN_DIM;     // 100000
    const int E = in_sizes[1];              // 3200000

    char* w = (char*)d_ws;
    size_t off = 0;
    auto carve = [&](size_t bytes) -> void* {
        void* p = w + off;
        off = (off + bytes + 255) & ~(size_t)255;
        return p;
    };
    signed char* xq = (signed char*)carve((size_t)M * OUT_DIM);             // 25.6 MB
    float* scales   = (float*)carve((size_t)M * 4);                         // 0.4 MB
    unsigned short* Wt = (unsigned short*)carve((size_t)IN_DIM * OUT_DIM * 2);
    int*  counts = (int*)carve((size_t)M * 4);
    int*  rs     = (int*)carve((size_t)(M + 1) * 4);
    int*  cursor = (int*)carve((size_t)M * 4);
    int*  bsum   = (int*)carve(256 * 4);
    int*  boff   = (int*)carve(256 * 4);
    int*  bcnt   = (int*)carve((NBUCK_MAX + 1) * 4);
    int*  bbase  = (int*)carve((NBUCK_MAX + 1) * 4);
    int*  bcur   = (int*)carve((NBUCK_MAX + 1) * 4);
    int2* ecv    = (int2*)carve((size_t)E * 8);                             // 25.6 MB (fallback only)
    int2* binned = (int2*)carve((size_t)E * 8);                             // 25.6 MB
    const int nbuck = (M + BROWS - 1) / BROWS;
    const bool use_binned = (off <= ws_size) && (nbuck <= NBUCK_MAX) && (M <= (1 << 17));

    k_convW<<<(IN_DIM * OUT_DIM + 255) / 256, 256, 0, stream>>>(Wk, Wt);
    k_gemm<<<(M + 127) / 128, 512, 0, stream>>>(features, Wt, xq, scales, M);

    if (use_binned) {
        hipMemsetAsync(bcnt, 0, (NBUCK_MAX + 1) * 4, stream);
        k_bhist<<<(E + 8191) / 8192, 512, 0, stream>>>(adj_rows, bcnt, E);
        k_bscan<<<1, NBUCK_MAX, 0, stream>>>(bcnt, bbase, bcur, nbuck, E);
        k_bin<<<(E + 8191) / 8192, 512, 0, stream>>>(adj_rows, adj_cols, adj_vals, scales, bcur, binned, E);
        k_aggb<<<nbuck, 512, 0, stream>>>(xq, scales, binned, bbase, skipw, bias, out, M);
    } else {
        hipMemsetAsync(counts, 0, (size_t)M * 4, stream);
        k_hist<<<(E / 4 + 255) / 256, 256, 0, stream>>>(adj_rows, counts, E);
        int nb = (M + 1023) / 1024;
        k_scan1<<<nb, 256, 0, stream>>>(counts, rs, bsum, M);
        k_scan2<<<1, 256, 0, stream>>>(bsum, boff, nb);
        k_scan3<<<nb, 256, 0, stream>>>(rs, cursor, boff, M, E);
        k_scatter<<<(E / 4 + 255) / 256, 256, 0, stream>>>(adj_rows, adj_cols, adj_vals, scales, cursor, ecv, E);
        k_agg<<<(M + 3) / 4, 256, 0, stream>>>(xq, scales, ecv, rs, skipw, bias, out, M);
    }
}